// Round 12
// baseline (408.918 us; speedup 1.0000x reference)
//
#include <hip/hip_runtime.h>

// ---------------- problem constants ----------------
#define Bb 4
#define Tt 512
#define Dd 1024
#define Hh 8
#define Dh 64
#define HD 512
#define Pp 2048
#define Mm (Bb*Tt)      // 2048
#define NAB (Pp+HD)     // 2560 : [xt | r]
#define NC  (3*HD)      // 1536 : [skip | q | k]
#define NDm (2*HD)      // 1024 : [v | o]

typedef float f32x4 __attribute__((ext_vector_type(4)));
typedef short short8 __attribute__((ext_vector_type(8)));
typedef unsigned short u16;

__device__ __forceinline__ float bf2f(u16 u) {
    return __uint_as_float(((unsigned int)u) << 16);
}
__device__ __forceinline__ u16 f2bf(float f) {
    unsigned int u = __float_as_uint(f);
    u = u + 0x7FFF + ((u >> 16) & 1);   // RNE
    return (u16)(u >> 16);
}
__device__ __forceinline__ float sigmoidf_(float z){ return 1.f/(1.f+__expf(-z)); }
__device__ __forceinline__ float siluf_(float z){ return z/(1.f+__expf(-z)); }
__device__ __forceinline__ void unp8(const u16* p, float* f) {
    uint4 v = *(const uint4*)p;
    const unsigned int* u = (const unsigned int*)&v;
    #pragma unroll
    for (int i = 0; i < 4; i++) {
        f[2*i]   = bf2f((u16)(u[i] & 0xffff));
        f[2*i+1] = bf2f((u16)(u[i] >> 16));
    }
}

struct Ptrs8  { const void* p[8];  };
struct PtrsS  { const void* p[18]; };

// ---------------- fallback: zero output ----------------
__global__ void zero_out_kernel(unsigned int* __restrict__ o, int n4) {
    int i = blockIdx.x * 256 + threadIdx.x;
    if (i < n4) o[i] = 0u;
}

// ---------------- dtype probe: bf16 vs f32 ----------------
__global__ void detect_kernel(const u16* __restrict__ xraw, int* __restrict__ flag) {
    __shared__ int bad_s;
    if (threadIdx.x == 0) bad_s = 0;
    __syncthreads();
    int bad = 0;
    for (int i = threadIdx.x; i < 4096; i += 256) {
        unsigned e = (xraw[i] >> 7) & 0xFF;
        if (e >= 135) bad++;
    }
    atomicAdd(&bad_s, bad);
    __syncthreads();
    if (threadIdx.x == 0) *flag = (bad_s < 100) ? 1 : 0;
}

// ---------------- canonicalize small tensors -> bf16 smallbuf ----------------
#define SO_LNW   0
#define SO_LNB   1024
#define SO_HLNW  2048
#define SO_HLNB  2560
#define SO_BL    3072
#define SO_BR    5120
#define SO_CW    5632
#define SO_CB    5640
#define SO_BSKIP 5648
#define SO_BI    6160
#define SO_BF    6168
#define SO_BO    6176
#define SO_BQ    6688
#define SO_BK    7200
#define SO_BV    7712
#define SO_BD    8224
#define SO_WI    9248
#define SO_WF    25632
#define SO_END   42016

__global__ __launch_bounds__(256) void canon_kernel(
    PtrsS S, const int* __restrict__ flag, u16* __restrict__ dst)
{
    constexpr int lens[18] = {1024,1024,512,512,2048,512,4,1,512,8,8,512,512,512,512,1024,16384,16384};
    constexpr int offs[18] = {SO_LNW,SO_LNB,SO_HLNW,SO_HLNB,SO_BL,SO_BR,SO_CW,SO_CB,
                              SO_BSKIP,SO_BI,SO_BF,SO_BO,SO_BQ,SO_BK,SO_BV,SO_BD,SO_WI,SO_WF};
    const bool isbf = (*flag != 0);
    int b = blockIdx.x;
    const void* src = S.p[b];
    int len = lens[b], off = offs[b];
    for (int i = threadIdx.x; i < len; i += 256) {
        dst[off + i] = isbf ? ((const u16*)src)[i] : f2bf(((const float*)src)[i]);
    }
}

// ---------------- weight transpose -> bf16^T, optional *0.125 (Wk) ----------------
__global__ __launch_bounds__(256) void transpose_kernel(
    Ptrs8 S, const int* __restrict__ flag,
    u16* __restrict__ WlrT, u16* __restrict__ WsqkT,
    u16* __restrict__ WvoT, u16* __restrict__ WdT)
{
    __shared__ u16 tile[32][33];
    const bool isbf = (*flag != 0);
    int bid = blockIdx.x;
    const void* src; u16* dst; int K, N; bool scale = false;
    if      (bid < 2048){ src=S.p[0]; dst=WlrT;              K=1024; N=2048; }
    else if (bid < 2560){ src=S.p[1]; dst=WlrT + 2048*1024;  K=1024; N=512;  bid-=2048; }
    else if (bid < 3584){ src=S.p[2]; dst=WsqkT;             K=2048; N=512;  bid-=2560; }
    else if (bid < 4608){ src=S.p[3]; dst=WsqkT + 512*2048;  K=2048; N=512;  bid-=3584; }
    else if (bid < 5632){ src=S.p[4]; dst=WsqkT + 1024*2048; K=2048; N=512;  bid-=4608; scale=true; }
    else if (bid < 6656){ src=S.p[5]; dst=WvoT;              K=2048; N=512;  bid-=5632; }
    else if (bid < 7680){ src=S.p[6]; dst=WvoT + 512*2048;   K=2048; N=512;  bid-=6656; }
    else               { src=S.p[7]; dst=WdT;                K=512;  N=1024; bid-=7680; }
    int tilesN = N >> 5;
    int k0 = (bid / tilesN) * 32, n0 = (bid % tilesN) * 32;
    int tx = threadIdx.x & 31, ty = threadIdx.x >> 5;
    #pragma unroll
    for (int r = 0; r < 4; r++) {
        int kr = ty + r*8;
        size_t idx = (size_t)(k0+kr)*N + n0 + tx;
        tile[kr][tx] = isbf ? ((const u16*)src)[idx] : f2bf(((const float*)src)[idx]);
    }
    __syncthreads();
    #pragma unroll
    for (int r = 0; r < 4; r++) {
        int nr = ty + r*8;
        u16 v = tile[tx][nr];
        if (scale) v = f2bf(bf2f(v) * 0.125f);   // exact exponent shift
        dst[(size_t)(n0+nr)*K + k0 + tx] = v;
    }
}

// ---------------- layernorm over D=1024 -> bf16 ----------------
__global__ __launch_bounds__(256) void ln_kernel(
    const void* __restrict__ xraw, const int* __restrict__ flag,
    const u16* __restrict__ small, u16* __restrict__ xn)
{
    const bool isbf = (*flag != 0);
    int m = blockIdx.x, t = threadIdx.x;
    float v0, v1, v2, v3;
    if (isbf) {
        ushort4 xv = *(const ushort4*)((const u16*)xraw + (size_t)m*Dd + t*4);
        v0 = bf2f(xv.x); v1 = bf2f(xv.y); v2 = bf2f(xv.z); v3 = bf2f(xv.w);
    } else {
        float4 xf = *(const float4*)((const float*)xraw + (size_t)m*Dd + t*4);
        v0 = xf.x; v1 = xf.y; v2 = xf.z; v3 = xf.w;
    }
    float s  = v0+v1+v2+v3;
    float ss = v0*v0 + v1*v1 + v2*v2 + v3*v3;
    #pragma unroll
    for (int o = 32; o; o >>= 1){ s += __shfl_xor(s,o); ss += __shfl_xor(ss,o); }
    __shared__ float sb[8];
    int wid = t >> 6;
    if ((t & 63) == 0){ sb[wid] = s; sb[4+wid] = ss; }
    __syncthreads();
    s  = sb[0]+sb[1]+sb[2]+sb[3];
    ss = sb[4]+sb[5]+sb[6]+sb[7];
    float mu = s * (1.f/Dd);
    float var = fmaxf(ss * (1.f/Dd) - mu*mu, 0.f);
    float rs = rsqrtf(var + 1e-6f);
    ushort4 wv = *(const ushort4*)&small[SO_LNW + t*4];
    ushort4 bv = *(const ushort4*)&small[SO_LNB + t*4];
    ushort4 o4;
    o4.x = f2bf((v0-mu)*rs*bf2f(wv.x) + bf2f(bv.x));
    o4.y = f2bf((v1-mu)*rs*bf2f(wv.y) + bf2f(bv.y));
    o4.z = f2bf((v2-mu)*rs*bf2f(wv.z) + bf2f(bv.z));
    o4.w = f2bf((v3-mu)*rs*bf2f(wv.w) + bf2f(bv.w));
    *(ushort4*)&xn[(size_t)m*Dd + t*4] = o4;
}

// ---------------- bf16 MFMA GEMM core: 1 wave / block, barrier-free ----------------
// Wave tile 64(M)x64(N), K in 32-steps. LDS: 4 buffers x (64x32 A + 64x32 B) = 32 KB,
// wave-private -> NO barriers. Each 64x32-u16 tile = 256 x 16B chunks = 4 DMA issues
// (chunk c: row=c>>2, seg=(c&3)*8; LDS = issue_base + lane*16, natural row-major).
// Prefetch depth 3; 8 issues/stage; s_waitcnt vmcnt(24) drains only the oldest tile.
// epi: 0 bf16, bias split 2048; 1 bf16, split 512/1024 (+0.125*b2);
//      2 bf16, split 512; 3 +b0+xres, dtype per flag.
__device__ __forceinline__ void gemm_core(
    const u16* __restrict__ A, int lda,
    const u16* __restrict__ Bt, int ldb,
    void* __restrict__ Cout, int ldc, int K,
    const u16* __restrict__ b0, const u16* __restrict__ b1,
    const u16* __restrict__ b2,
    const void* __restrict__ xres, const int* __restrict__ flag,
    int epi, int m0, int n0, u16* As, u16* Bs)
{
    const int lane = threadIdx.x & 63;
    const int ln16 = lane & 15;
    const int quad = lane >> 4;

    f32x4 acc[4][4];
    #pragma unroll
    for (int i = 0; i < 4; i++)
        #pragma unroll
        for (int j = 0; j < 4; j++) acc[i][j] = (f32x4){0.f,0.f,0.f,0.f};

    // stage one 32-wide K tile: A 64x32 u16 (256 chunks, 4 issues) + B same.
    auto stage = [&](int k0, int bi) {
        u16* Ad = As + bi*2048;
        u16* Bd = Bs + bi*2048;
        #pragma unroll
        for (int p = 0; p < 4; p++) {
            int c = p*64 + lane;
            int row = c >> 2, seg = (c & 3) << 3;
            __builtin_amdgcn_global_load_lds(
                (const __attribute__((address_space(1))) void*)(A + (size_t)(m0+row)*lda + k0 + seg),
                (__attribute__((address_space(3))) void*)(Ad + p*512), 16, 0, 0);
        }
        #pragma unroll
        for (int p = 0; p < 4; p++) {
            int c = p*64 + lane;
            int row = c >> 2, seg = (c & 3) << 3;
            __builtin_amdgcn_global_load_lds(
                (const __attribute__((address_space(1))) void*)(Bt + (size_t)(n0+row)*ldb + k0 + seg),
                (__attribute__((address_space(3))) void*)(Bd + p*512), 16, 0, 0);
        }
    };

    const int nk = K >> 5;
    stage(0, 0);
    if (nk > 1) stage(32, 1);
    if (nk > 2) stage(64, 2);
    for (int kb = 0; kb < nk; kb++) {
        if (kb + 3 < nk) {
            stage((kb+3) << 5, (kb+3) & 3);
            asm volatile("s_waitcnt vmcnt(24)" ::: "memory");   // oldest tile landed
        } else if (kb + 2 < nk) {
            asm volatile("s_waitcnt vmcnt(16)" ::: "memory");
        } else if (kb + 1 < nk) {
            asm volatile("s_waitcnt vmcnt(8)" ::: "memory");
        } else {
            asm volatile("s_waitcnt vmcnt(0)" ::: "memory");
        }
        const u16* Ac = As + (kb & 3)*2048;
        const u16* Bc = Bs + (kb & 3)*2048;
        short8 af[4], bfr[4];
        #pragma unroll
        for (int mi = 0; mi < 4; mi++)
            af[mi] = *(const short8*)&Ac[(mi*16 + ln16)*32 + quad*8];
        #pragma unroll
        for (int ni = 0; ni < 4; ni++)
            bfr[ni] = *(const short8*)&Bc[(ni*16 + ln16)*32 + quad*8];
        #pragma unroll
        for (int mi = 0; mi < 4; mi++)
            #pragma unroll
            for (int ni = 0; ni < 4; ni++)
                acc[mi][ni] = __builtin_amdgcn_mfma_f32_16x16x32_bf16(
                    af[mi], bfr[ni], acc[mi][ni], 0, 0, 0);
        // wave-private buffers: ds_reads of iter kb-1 completed (lgkmcnt before
        // their MFMAs) before this iter's stage overwrites that buffer.
    }

    bool isbf = true;
    if (epi == 3) isbf = (*flag != 0);
    #pragma unroll
    for (int mi = 0; mi < 4; mi++) {
        #pragma unroll
        for (int ni = 0; ni < 4; ni++) {
            int col = n0 + ni*16 + ln16;
            #pragma unroll
            for (int r = 0; r < 4; r++) {
                int row = m0 + mi*16 + quad*4 + r;
                float v = acc[mi][ni][r];
                if (epi == 0) {
                    v += (col < 2048) ? bf2f(b0[col]) : bf2f(b1[col-2048]);
                    ((u16*)Cout)[(size_t)row*ldc + col] = f2bf(v);
                } else if (epi == 1) {
                    v += (col < 512) ? bf2f(b0[col])
                       : (col < 1024 ? bf2f(b1[col-512]) : 0.125f*bf2f(b2[col-1024]));
                    ((u16*)Cout)[(size_t)row*ldc + col] = f2bf(v);
                } else if (epi == 2) {
                    v += (col < 512) ? bf2f(b0[col]) : bf2f(b1[col-512]);
                    ((u16*)Cout)[(size_t)row*ldc + col] = f2bf(v);
                } else {
                    size_t ridx = (size_t)row*Dd + col;
                    float res = isbf ? bf2f(((const u16*)xres)[ridx])
                                     : ((const float*)xres)[ridx];
                    v += bf2f(b0[col]) + res;
                    if (isbf) ((u16*)Cout)[(size_t)row*ldc + col] = f2bf(v);
                    else      ((float*)Cout)[(size_t)row*ldc + col] = v;
                }
            }
        }
    }
}

__global__ __launch_bounds__(64) void gemm_single_kernel(
    const u16* __restrict__ A, int lda,
    const u16* __restrict__ Bt, int ldb,
    void* __restrict__ Cout, int ldc, int K,
    const u16* __restrict__ b0, const u16* __restrict__ b1,
    const u16* __restrict__ b2,
    const void* __restrict__ xres, const int* __restrict__ flag, int epi)
{
    __shared__ u16 As[4*64*32];
    __shared__ u16 Bs[4*64*32];
    gemm_core(A, lda, Bt, ldb, Cout, ldc, K, b0, b1, b2, xres, flag, epi,
              blockIdx.y*64, blockIdx.x*64, As, Bs);
}

// merged gemm1 (sqk) + gemm2 (vo): both K=2048, one 1280-block launch
__global__ __launch_bounds__(64) void gemm_pair_kernel(
    const u16* __restrict__ A1, int lda1, const u16* __restrict__ Bt1,
    void* __restrict__ C1, int ldc1,
    const u16* __restrict__ b10, const u16* __restrict__ b11, const u16* __restrict__ b12,
    int nt1,
    const u16* __restrict__ A2, int lda2, const u16* __restrict__ Bt2,
    void* __restrict__ C2, int ldc2,
    const u16* __restrict__ b20, const u16* __restrict__ b21,
    int K, const int* __restrict__ flag)
{
    __shared__ u16 As[4*64*32];
    __shared__ u16 Bs[4*64*32];
    int bx = blockIdx.x, m0 = blockIdx.y*64;
    if (bx < nt1)
        gemm_core(A1, lda1, Bt1, 2048, C1, ldc1, K, b10, b11, b12,
                  nullptr, flag, 1, m0, bx*64, As, Bs);
    else
        gemm_core(A2, lda2, Bt2, 2048, C2, ldc2, K, b20, b21, nullptr,
                  nullptr, flag, 2, m0, (bx-nt1)*64, As, Bs);
}

// ---------------- causal conv over feature axis + silu ----------------
__global__ __launch_bounds__(256) void conv_kernel(
    const u16* __restrict__ xtr, const u16* __restrict__ small,
    u16* __restrict__ xc)
{
    int m = blockIdx.x, t = threadIdx.x;
    int p0 = t * 8;
    const u16* rowp = xtr + (size_t)m * NAB;
    uint4 cur = *(const uint4*)&rowp[p0];
    uint4 prv;
    if (t > 0) prv = *(const uint4*)&rowp[p0-8];
    else { prv.x = prv.y = prv.z = prv.w = 0u; }
    float c16[16];
    const unsigned int* pu = (const unsigned int*)&prv;
    const unsigned int* cu = (const unsigned int*)&cur;
    #pragma unroll
    for (int i = 0; i < 4; i++) {
        c16[2*i]     = bf2f((u16)(pu[i] & 0xffff));
        c16[2*i+1]   = bf2f((u16)(pu[i] >> 16));
        c16[8+2*i]   = bf2f((u16)(cu[i] & 0xffff));
        c16[8+2*i+1] = bf2f((u16)(cu[i] >> 16));
    }
    float w0 = bf2f(small[SO_CW+0]), w1 = bf2f(small[SO_CW+1]);
    float w2 = bf2f(small[SO_CW+2]), w3 = bf2f(small[SO_CW+3]);
    float bb = bf2f(small[SO_CB]);
    unsigned int ou[4];
    #pragma unroll
    for (int jp = 0; jp < 4; jp++) {
        int j = 2*jp;
        float z0 = siluf_(bb + w0*c16[j+5] + w1*c16[j+6] + w2*c16[j+7] + w3*c16[j+8]);
        j++;
        float z1 = siluf_(bb + w0*c16[j+5] + w1*c16[j+6] + w2*c16[j+7] + w3*c16[j+8]);
        ou[jp] = (unsigned int)f2bf(z0) | ((unsigned int)f2bf(z1) << 16);
    }
    *(uint4*)&xc[(size_t)m*Pp + p0] = *(uint4*)ou;
}

// ---------------- gate GEMM (N=8 each) + softcap ----------------
__global__ __launch_bounds__(256) void gate_kernel(
    const u16* __restrict__ xc, const u16* __restrict__ small,
    float* __restrict__ ipre, float* __restrict__ fpre)
{
    const u16* Wi  = small + SO_WI;
    const u16* Wf  = small + SO_WF;
    int w = threadIdx.x >> 6, lane = threadIdx.x & 63;
    int m = blockIdx.x*4 + w;
    float ai[8], af_[8];
    #pragma unroll
    for (int g = 0; g < 8; g++){ ai[g] = 0.f; af_[g] = 0.f; }
    for (int kb = 0; kb < 32; kb++) {
        int k = kb*64 + lane;
        float xv = bf2f(xc[(size_t)m*Pp + k]);
        uint4 wiu = *(const uint4*)&Wi[(size_t)k*8];
        uint4 wfu = *(const uint4*)&Wf[(size_t)k*8];
        const unsigned int* wi_ = (const unsigned int*)&wiu;
        const unsigned int* wf_ = (const unsigned int*)&wfu;
        #pragma unroll
        for (int i = 0; i < 4; i++) {
            ai[2*i]   += xv * bf2f((u16)(wi_[i] & 0xffff));
            ai[2*i+1] += xv * bf2f((u16)(wi_[i] >> 16));
            af_[2*i]  += xv * bf2f((u16)(wf_[i] & 0xffff));
            af_[2*i+1]+= xv * bf2f((u16)(wf_[i] >> 16));
        }
    }
    #pragma unroll
    for (int o = 32; o; o >>= 1) {
        #pragma unroll
        for (int g = 0; g < 8; g++) {
            ai[g]  += __shfl_xor(ai[g],  o);
            af_[g] += __shfl_xor(af_[g], o);
        }
    }
    if (lane == 0) {
        #pragma unroll
        for (int g = 0; g < 8; g++) {
            ipre[(size_t)m*8 + g] = 15.f * tanhf((ai[g]  + bf2f(small[SO_BI+g])) * (1.f/15.f));
            fpre[(size_t)m*8 + g] = 15.f * tanhf((af_[g] + bf2f(small[SO_BF+g])) * (1.f/15.f));
        }
    }
}

// ---------------- parallel gate scan (max-plus scan) -> log-space chunk gates ----------------
__global__ __launch_bounds__(512) void gatescan_kernel(
    const float* __restrict__ ipre, const float* __restrict__ fpre,
    float* __restrict__ LPa, float* __restrict__ li, float* __restrict__ LPtot)
{
    int bh = blockIdx.x;
    int b = bh >> 3, h = bh & 7;
    int t = threadIdx.x;
    int lane = t & 63, w = t >> 6;     // wave w == chunk w (64 timesteps)
    size_t idx = ((size_t)(b*Tt + t))*8 + h;
    float iv = ipre[idx], fv = fpre[idx];
    float A = fv, Bv = iv;
    #pragma unroll
    for (int o = 1; o < 64; o <<= 1) {     // inclusive scan within wave
        float pA = __shfl_up(A, o), pB = __shfl_up(Bv, o);
        if (lane >= o) {
            Bv = fmaxf(A + pB, Bv);        // compose(prev, cur)
            A  = A + pA;
        }
    }
    __shared__ float aggA[8], aggB[8], mprev_s[8];
    if (lane == 63) { aggA[w] = A; aggB[w] = Bv; }
    __syncthreads();
    if (t == 0) {
        float m = 0.f;
        #pragma unroll
        for (int j = 0; j < 8; j++) {
            mprev_s[j] = m;
            m = fmaxf(aggA[j] + m, aggB[j]);
        }
    }
    __syncthreads();
    float mprev_w = mprev_s[w];            // m at end of previous chunk (m_{-1}=0)
    float m_t = fmaxf(A + mprev_w, Bv);    // inclusive m at t
    float m_tm1 = __shfl_up(m_t, 1);
    if (lane == 0) m_tm1 = mprev_w;
    float li_t = iv - m_t;                 // log ie <= 0
    float g = fv + m_tm1 - m_t;            // log fe <= 0
    float lp = g;                          // within-chunk inclusive cumsum
    #pragma unroll
    for (int o = 1; o < 64; o <<= 1) {
        float p = __shfl_up(lp, o);
        if (lane >= o) lp += p;
    }
    LPa[(size_t)bh*Tt + t] = lp;
    li[(size_t)bh*Tt + t] = li_t;
    if (lane == 63) LPtot[bh*8 + w] = lp;
}

// ---------------- chunk outer products: B = sum_i w_i v_i k_i^T ----------------
__global__ __launch_bounds__(256) void chunk_outer_kernel(
    const u16* __restrict__ sqk, const u16* __restrict__ vo,
    const float* __restrict__ LPa, const float* __restrict__ li,
    const float* __restrict__ LPtot,
    float* __restrict__ B, float* __restrict__ bn)
{
    int blk = blockIdx.x;          // bh*8 + c
    int bh = blk >> 3, c = blk & 7;
    int b = bh >> 3, h = bh & 7;
    __shared__ u16 kS[64*64], vS[64*64];
    __shared__ float wS[64];
    int tid = threadIdx.x;
    for (int r = tid; r < 512; r += 256) {
        int i = r >> 3, seg = (r & 7) * 8;
        size_t m = (size_t)b*Tt + c*64 + i;
        *(uint4*)&kS[i*64+seg] = *(const uint4*)&sqk[m*NC + 1024 + h*64 + seg];
        *(uint4*)&vS[i*64+seg] = *(const uint4*)&vo[m*NDm + h*64 + seg];
    }
    if (tid < 64) {
        float lpt = LPtot[bh*8 + c];
        int t = c*64 + tid;
        wS[tid] = __expf(lpt - LPa[(size_t)bh*Tt + t] + li[(size_t)bh*Tt + t]);
    }
    __syncthreads();
    int e = tid & 63, d0 = (tid >> 6) << 4;
    float acc[16];
    #pragma unroll
    for (int z = 0; z < 16; z++) acc[z] = 0.f;
    for (int i = 0; i < 64; i++) {
        float wk = wS[i] * bf2f(kS[i*64 + e]);
        float v16[16];
        unp8(&vS[i*64 + d0], v16);
        unp8(&vS[i*64 + d0 + 8], v16 + 8);
        #pragma unroll
        for (int z = 0; z < 16; z++) acc[z] += wk * v16[z];
    }
    float* Bp = B + (size_t)blk*4096;
    #pragma unroll
    for (int z = 0; z < 16; z++) Bp[(d0+z)*64 + e] = acc[z];
    if (tid < 64) {
        float a = 0.f;
        for (int i = 0; i < 64; i++) a += wS[i] * bf2f(kS[i*64 + tid]);
        bn[blk*64 + tid] = a;
    }
}

// ---------------- sequential chunk-state pass (8 steps) ----------------
__global__ __launch_bounds__(256) void state_pass_kernel(
    const float* __restrict__ B, const float* __restrict__ bn,
    const float* __restrict__ LPtot,
    float* __restrict__ Cinit, float* __restrict__ ninit)
{
    int bh = blockIdx.x, tid = threadIdx.x;
    float C[16];
    #pragma unroll
    for (int j = 0; j < 16; j++) C[j] = 0.f;
    float nv = 1.f;
    for (int c = 0; c < 8; c++) {
        float pc = __expf(LPtot[bh*8 + c]);
        const float* Bp = B + ((size_t)bh*8 + c)*4096;
        float* Cp = Cinit + ((size_t)bh*8 + c)*4096;
        #pragma unroll
        for (int j = 0; j < 16; j++) {
            Cp[tid*16 + j] = C[j];
            C[j] = pc*C[j] + Bp[tid*16 + j];
        }
        if (tid < 64) {
            ninit[(bh*8 + c)*64 + tid] = nv;
            nv = pc*nv + bn[(bh*8 + c)*64 + tid];
        }
    }
}

// ---------------- intra-chunk attention-form pass ----------------
__global__ __launch_bounds__(256) void intra_kernel(
    const u16* __restrict__ sqk, const u16* __restrict__ vo,
    const float* __restrict__ LPa, const float* __restrict__ li,
    const float* __restrict__ Cinit, const float* __restrict__ ninit,
    u16* __restrict__ hraw)
{
    int blk = blockIdx.x;          // bh*8 + c
    int bh = blk >> 3, c = blk & 7;
    int b = bh >> 3, h = bh & 7;
    __shared__ u16 qS[64*64], kS[64*64], vS[64*64];
    __shared__ float GS[64*64];
    __shared__ float CS[64*64];
    __shared__ float lpS[64], liS[64], nS[64], denS[64];
    int tid = threadIdx.x;
    for (int r = tid; r < 512; r += 256) {
        int i = r >> 3, seg = (r & 7) * 8;
        size_t m = (size_t)b*Tt + c*64 + i;
        *(uint4*)&qS[i*64+seg] = *(const uint4*)&sqk[m*NC + 512 + h*64 + seg];
        *(uint4*)&kS[i*64+seg] = *(const uint4*)&sqk[m*NC + 1024 + h*64 + seg];
        *(uint4*)&vS[i*64+seg] = *(const uint4*)&vo[m*NDm + h*64 + seg];
    }
    for (int r = tid; r < 4096; r += 256) CS[r] = Cinit[(size_t)blk*4096 + r];
    if (tid < 64) {
        lpS[tid] = LPa[(size_t)bh*Tt + c*64 + tid];
        liS[tid] = li[(size_t)bh*Tt + c*64 + tid];
        nS[tid]  = ninit[blk*64 + tid];
    }
    __syncthreads();

    // phase 1: masked scaled scores G'[j,i]
    {
        int j = tid & 63, i0 = (tid >> 6) << 4;
        float acc[16];
        #pragma unroll
        for (int z = 0; z < 16; z++) acc[z] = 0.f;
        for (int seg = 0; seg < 64; seg += 8) {
            float q8[8];
            unp8(&qS[j*64 + seg], q8);
            #pragma unroll
            for (int z = 0; z < 16; z++) {
                float k8[8];
                unp8(&kS[(i0+z)*64 + seg], k8);
                float a = acc[z];
                #pragma unroll
                for (int e = 0; e < 8; e++) a += q8[e]*k8[e];
                acc[z] = a;
            }
        }
        float lpj = lpS[j];
        #pragma unroll
        for (int z = 0; z < 16; z++) {
            int i = i0 + z;
            GS[j*64 + i] = (i <= j) ? __expf(lpj - lpS[i] + liS[i]) * acc[z] : 0.f;
        }
    }
    __syncthreads();

    // phase 2: num = G'V + exp(lp_j) * Cinit q_j ; den
    int j = tid & 63, d0 = (tid >> 6) << 4;
    float num[16];
    #pragma unroll
    for (int z = 0; z < 16; z++) num[z] = 0.f;
    for (int i = 0; i < 64; i++) {
        float g = GS[j*64 + i];
        float v16[16];
        unp8(&vS[i*64 + d0], v16);
        unp8(&vS[i*64 + d0 + 8], v16 + 8);
        #pragma unroll
        for (int z = 0; z < 16; z++) num[z] += g * v16[z];
    }
    float pj = __expf(lpS[j]);
    for (int es = 0; es < 16; es++) {
        uint2 uv = *(const uint2*)&qS[j*64 + es*4];
        float q0 = pj*bf2f((u16)(uv.x & 0xffff)), q1 = pj*bf2f((u16)(uv.x >> 16));
        float q2 = pj*bf2f((u16)(uv.y & 0xffff)), q3 = pj*bf2f((u16)(uv.y >> 16));
        #pragma unroll
        for (int z = 0; z < 16; z++) {
            float4 cv = *(const float4*)&CS[(d0+z)*64 + es*4];
            num[z] += q0*cv.x + q1*cv.y + q2*cv.z + q3*cv.w;
        }
    }
    if (tid < 64) {
        int jj = tid;
        float s = 0.f;
        for (int i = 0; i < 64; i++) s += GS[jj*64 + i];
        float dn = 0.f;
        for (int e = 0; e < 64; e++) dn += nS[e] * bf2f(qS[jj*64 + e]);
        denS[jj] = fmaxf(__expf(lpS[jj])*dn + s, 1.f);
    }
    __syncthreads();

    // phase 3: h = num/den -> hraw
    float rden = 1.f / denS[j];
    size_t m = (size_t)b*Tt + c*64 + j;
    unsigned int w[8];
    #pragma unroll
    for (int z = 0; z < 8; z++)
        w[z] = (unsigned int)f2bf(num[2*z]*rden) | ((unsigned int)f2bf(num[2*z+1]*rden) << 16);
    u16* hp = &hraw[m*HD + h*64 + d0];
    *(uint4*)hp       = make_uint4(w[0], w[1], w[2], w[3]);
    *(uint4*)(hp + 8) = make_uint4(w[4], w[5], w[6], w[7]);
}

// ---------------- fused o*sigmoid, head-LN, +skip, *silu(r) ----------------
__global__ __launch_bounds__(256) void fuse_kernel(
    const u16* __restrict__ hraw, const u16* __restrict__ vo,
    const u16* __restrict__ sqk, const u16* __restrict__ xtr,
    const u16* __restrict__ small, u16* __restrict__ y)
{
    int wid = blockIdx.x*4 + (threadIdx.x >> 6);
    int l = threadIdx.x & 63;
    int m = wid >> 3, h = wid & 7;
    float hv = bf2f(hraw[(size_t)m*HD + h*64 + l]);
    float oz = bf2f(vo[(size_t)m*NDm + 512 + h*64 + l]);
    float xv = sigmoidf_(oz) * hv;
    float s = xv, ss = xv*xv;
    #pragma unroll
    for (int o = 32; o; o >>= 1){ s += __shfl_xor(s,o); ss += __shfl_xor(ss,o); }
    float mu = s * (1.f/64.f);
    float var = fmaxf(ss * (1.f/64.f) - mu*mu, 0.f);
    float hn = (xv - mu) * rsqrtf(var + 1e-6f) * bf2f(small[SO_HLNW + h*64 + l])
             + bf2f(small[SO_HLNB + h*64 + l]);
    float skip = bf2f(sqk[(size_t)m*NC + h*64 + l]);
    float r = bf2f(xtr[(size_t)m*NAB + 2048 + h*64 + l]);
    y[(size_t)m*HD + h*64 + l] = f2bf((hn + skip) * siluf_(r));
}

// ---------------- launch ----------------
extern "C" void kernel_launch(void* const* d_in, const int* in_sizes, int n_in,
                              void* d_out, int out_size, void* d_ws, size_t ws_size,
                              hipStream_t stream)
{
    (void)in_sizes; (void)n_in;
    const void* x      = d_in[0];
    const void* ln_w   = d_in[1];
    const void* ln_b   = d_in[2];
    const void* hln_w  = d_in[3];
    const void* hln_b  = d_in[4];
    const void* Wl     = d_in[5];
    const void* bl     = d_in[6];
    const void* Wr     = d_in[7];
    const void* br     = d_in[8];
    const void* conv_w = d_in[9];
    const void* conv_b = d_in[10];
    const void* Wskip  = d_in[11];
    const void* bskip  = d_in[12];
    const void* Wi     = d_in[13];
    const void* bi     = d_in[14];
    const void* Wf     = d_in[15];
    const void* bf     = d_in[16];
    const void* Wo     = d_in[17];
    const void* bo     = d_in[18];
    const void* Wq     = d_in[19];
    const void* bq     = d_in[20];
    const void* Wk     = d_in[21];
    const void* bk     = d_in[22];
    const void* Wv     = d_in[23];
    const void* bv     = d_in[24];
    const void* Wd     = d_in[25];
    const void* bd     = d_in[26];

    // ---- workspace layout ----
    const size_t SZ_flag  = 256;
    const size_t SZ_small = ((size_t)SO_END*2 + 255) & ~(size_t)255;
    const size_t SZ_WlrT  = (size_t)NAB*1024*2;   //  5,242,880
    const size_t SZ_WsqkT = (size_t)NC*2048*2;    //  6,291,456
    const size_t SZ_WvoT  = (size_t)NDm*2048*2;   //  4,194,304
    const size_t SZ_WdT   = (size_t)1024*512*2;   //  1,048,576
    const size_t SZ_xn    = (size_t)Mm*Dd*2;      //  4,194,304
    const size_t SZ_xtr   = (size_t)Mm*NAB*2;     // 10,485,760
    const size_t SZ_xc    = (size_t)Mm*Pp*2;      //  8,388,608
    const size_t SZ_sqk   = (size_t)Mm*NC*2;      //  6,291,456
    const size_t NEED = SZ_flag+SZ_small+SZ_WlrT+SZ_WsqkT+SZ_WvoT+SZ_WdT+SZ_xn+SZ_xtr+SZ_xc+SZ_sqk;

    if (ws_size < NEED) {
        int n4 = (out_size + 1) / 2;
        zero_out_kernel<<<(n4+255)/256, 256, 0, stream>>>((unsigned int*)d_out, n4);
        return;
    }

    char* wsp = (char*)d_ws;
    int* flag   = (int*)wsp;
    u16* small  = (u16*)(wsp + SZ_flag);
    u16* WlrT   = (u16*)(wsp + SZ_flag + SZ_small);
    u16* WsqkT  = (u16*)((char*)WlrT + SZ_WlrT);
    u16* WvoT   = (u16*)((char*)WsqkT + SZ_WsqkT);
    u16* WdT    = (u16*)((char*)WvoT + SZ_WvoT);
    char* regE  = (char*)WdT + SZ_WdT;            // xn region
    u16* xn     = (u16*)regE;
    u16* xtr    = (u16*)(regE + SZ_xn);
    u16* xc     = (u16*)(regE + SZ_xn + SZ_xtr);
    u16* sqk    = (u16*)(regE + SZ_xn + SZ_xtr + SZ_xc);
    // aliases (lifetimes disjoint):
    u16* vo     = WlrT;                 // 4 MB <= SZ_WlrT; WlrT dead after gemm0
    u16* y      = WvoT;                 // 2 MB; written in fuse, after Cinit consumed
    float* ipre = (float*)regE;         // xn dead after gemm0
    float* fpre = (float*)(regE + 65536);
    float* LPa  = (float*)(regE + 2*65536);
    float* li   = (float*)(regE + 3*65536);
    float* LPtot= (float*)(regE + 4*65536);           //   1 KB
    u16* hraw   = (u16*)(regE + 4*65536 + 4096);      //   2 MB
    float* Bc   = (float*)WsqkT;                       //   4 MB  (WsqkT dead after gemm1)
    float* bn   = (float*)((char*)WsqkT + 4194304);    //  64 KB
    float* ninit= (float*)((char*)WsqkT + 4259840);    //  64 KB
    float* Cinit= (float*)WvoT;                        //   4 MB  (WvoT dead after gemm2)

    detect_kernel<<<1, 256, 0, stream>>>((const u16*)x, flag);

    PtrsS SS;
    SS.p[0]=ln_w;  SS.p[1]=ln_b;   SS.p[2]=hln_w; SS.p[3]=hln_b; SS.p[4]=bl;
    SS.p[5]=br;    SS.p[6]=conv_w; SS.p[7]=conv_b;SS.p[8]=bskip; SS.p[9]=bi;
    SS.p[10]=bf;   SS.p[11]=bo;    SS.p[12]=bq;   SS.p[13]=bk;   SS.p[14]=bv;
    SS.p[15]=bd;   SS.p[16]=Wi;    SS.p[17]=Wf;
    canon_kernel<<<18, 256, 0, stream>>>(SS, flag, small);

    Ptrs8 SW;
    SW.p[0]=Wl; SW.p[1]=Wr; SW.p[2]=Wskip; SW.p[3]=Wq;
    SW.p[4]=Wk; SW.p[5]=Wv; SW.p[6]=Wo;    SW.p[7]=Wd;
    transpose_kernel<<<8192, 256, 0, stream>>>(SW, flag, WlrT, WsqkT, WvoT, WdT);

    ln_kernel<<<Mm, 256, 0, stream>>>(x, flag, small, xn);
    // xtr = xn @ [Wl|Wr] + [bl|br]   (40x32 = 1280 blocks, 1 wave each)
    gemm_single_kernel<<<dim3(NAB/64, Mm/64), 64, 0, stream>>>(
        xn, Dd, WlrT, 1024, xtr, NAB, 1024,
        small+SO_BL, small+SO_BR, nullptr, nullptr, flag, 0);
    conv_kernel<<<Mm, 256, 0, stream>>>(xtr, small, xc);
    // sqk = xc @ [Wskip|Wq|Wk/8] ; vo = xt @ [Wv|Wo]  (40x32 = 1280 blocks)
    gemm_pair_kernel<<<dim3(NC/64 + NDm/64, Mm/64), 64, 0, stream>>>(
        xc, Pp, WsqkT, sqk, NC,
        small+SO_BSKIP, small+SO_BQ, small+SO_BK, NC/64,
        xtr, NAB, WvoT, vo, NDm,
        small+SO_BV, small+SO_BO,
        2048, flag);
    gate_kernel<<<Mm/4, 256, 0, stream>>>(xc, small, ipre, fpre);
    gatescan_kernel<<<32, 512, 0, stream>>>(ipre, fpre, LPa, li, LPtot);
    chunk_outer_kernel<<<256, 256, 0, stream>>>(sqk, vo, LPa, li, LPtot, Bc, bn);
    state_pass_kernel<<<32, 256, 0, stream>>>(Bc, bn, LPtot, Cinit, ninit);
    intra_kernel<<<256, 256, 0, stream>>>(sqk, vo, LPa, li, Cinit, ninit, hraw);
    fuse_kernel<<<Mm*Hh/4, 256, 0, stream>>>(hraw, vo, sqk, xtr, small, y);
    // out = (y @ Wd + bd + x), dtype per flag   (16x32 = 512 blocks)
    gemm_single_kernel<<<dim3(Dd/64, Mm/64), 64, 0, stream>>>(
        y, HD, WdT, 512, d_out, Dd, 512,
        small+SO_BD, nullptr, nullptr, x, flag, 3);
}

// Round 13
// 313.603 us; speedup vs baseline: 1.3039x; 1.3039x over previous
//
#include <hip/hip_runtime.h>

// ---------------- problem constants ----------------
#define Bb 4
#define Tt 512
#define Dd 1024
#define Hh 8
#define Dh 64
#define HD 512
#define Pp 2048
#define Mm (Bb*Tt)      // 2048
#define NAB (Pp+HD)     // 2560 : [xt | r]
#define NC  (3*HD)      // 1536 : [skip | q | k]
#define NDm (2*HD)      // 1024 : [v | o]

typedef float f32x4 __attribute__((ext_vector_type(4)));
typedef short short8 __attribute__((ext_vector_type(8)));
typedef unsigned short u16;

__device__ __forceinline__ float bf2f(u16 u) {
    return __uint_as_float(((unsigned int)u) << 16);
}
__device__ __forceinline__ u16 f2bf(float f) {
    unsigned int u = __float_as_uint(f);
    u = u + 0x7FFF + ((u >> 16) & 1);   // RNE
    return (u16)(u >> 16);
}
__device__ __forceinline__ float sigmoidf_(float z){ return 1.f/(1.f+__expf(-z)); }
__device__ __forceinline__ float siluf_(float z){ return z/(1.f+__expf(-z)); }
__device__ __forceinline__ void unp8(const u16* p, float* f) {
    uint4 v = *(const uint4*)p;
    const unsigned int* u = (const unsigned int*)&v;
    #pragma unroll
    for (int i = 0; i < 4; i++) {
        f[2*i]   = bf2f((u16)(u[i] & 0xffff));
        f[2*i+1] = bf2f((u16)(u[i] >> 16));
    }
}
// wave-uniform dtype probe: first 64 u16 of x. bf16 N(0,1): exp<=129 always.
// f32 viewed as u16: even halfwords uniform -> ~15/64 have exp>=135.
__device__ __forceinline__ bool probe_bf16(const u16* x) {
    unsigned v = x[threadIdx.x & 63];
    unsigned e = (v >> 7) & 0xFF;
    unsigned long long m = __ballot(e >= 135);
    return __popcll(m) < 8;
}

struct Ptrs8  { const void* p[8];  };
struct PtrsS  { const void* p[18]; };

// ---------------- fallback: zero output ----------------
__global__ void zero_out_kernel(unsigned int* __restrict__ o, int n4) {
    int i = blockIdx.x * 256 + threadIdx.x;
    if (i < n4) o[i] = 0u;
}

// ---------------- small-tensor canon offsets ----------------
#define SO_LNW   0
#define SO_LNB   1024
#define SO_HLNW  2048
#define SO_HLNB  2560
#define SO_BL    3072
#define SO_BR    5120
#define SO_CW    5632
#define SO_CB    5640
#define SO_BSKIP 5648
#define SO_BI    6160
#define SO_BF    6168
#define SO_BO    6176
#define SO_BQ    6688
#define SO_BK    7200
#define SO_BV    7712
#define SO_BD    8224
#define SO_WI    9248
#define SO_WF    25632
#define SO_END   42016

// ---------------- fused prep: canon(18) + transpose(2048) + ln(2048) ----------------
#define NB_CANON 18
#define NB_TRANS 2048
__global__ __launch_bounds__(256) void prep_kernel(
    PtrsS S, Ptrs8 SW, const void* __restrict__ xraw,
    const void* __restrict__ lnw_raw, const void* __restrict__ lnb_raw,
    u16* __restrict__ small,
    u16* __restrict__ WlrT, u16* __restrict__ WsqkT,
    u16* __restrict__ WvoT, u16* __restrict__ WdT,
    u16* __restrict__ xn)
{
    const bool isbf = probe_bf16((const u16*)xraw);
    int bid = blockIdx.x;
    int tid = threadIdx.x;

    if (bid < NB_CANON) {
        constexpr int lens[18] = {1024,1024,512,512,2048,512,4,1,512,8,8,512,512,512,512,1024,16384,16384};
        constexpr int offs[18] = {SO_LNW,SO_LNB,SO_HLNW,SO_HLNB,SO_BL,SO_BR,SO_CW,SO_CB,
                                  SO_BSKIP,SO_BI,SO_BF,SO_BO,SO_BQ,SO_BK,SO_BV,SO_BD,SO_WI,SO_WF};
        const void* src = S.p[bid];
        int len = lens[bid], off = offs[bid];
        for (int i = tid; i < len; i += 256)
            small[off + i] = isbf ? ((const u16*)src)[i] : f2bf(((const float*)src)[i]);
        return;
    }
    bid -= NB_CANON;
    if (bid < NB_TRANS) {
        // 64x64 transpose tiles
        __shared__ u16 tile[64][65];
        const void* src; u16* dst; int K, N; bool scale = false;
        if      (bid < 512) { src=SW.p[0]; dst=WlrT;              K=1024; N=2048; }
        else if (bid < 640) { src=SW.p[1]; dst=WlrT + 2048*1024;  K=1024; N=512;  bid-=512; }
        else if (bid < 896) { src=SW.p[2]; dst=WsqkT;             K=2048; N=512;  bid-=640; }
        else if (bid < 1152){ src=SW.p[3]; dst=WsqkT + 512*2048;  K=2048; N=512;  bid-=896; }
        else if (bid < 1408){ src=SW.p[4]; dst=WsqkT + 1024*2048; K=2048; N=512;  bid-=1152; scale=true; }
        else if (bid < 1664){ src=SW.p[5]; dst=WvoT;              K=2048; N=512;  bid-=1408; }
        else if (bid < 1920){ src=SW.p[6]; dst=WvoT + 512*2048;   K=2048; N=512;  bid-=1664; }
        else                { src=SW.p[7]; dst=WdT;               K=512;  N=1024; bid-=1920; }
        int tilesN = N >> 6;
        int k0 = (bid / tilesN) * 64, n0 = (bid % tilesN) * 64;
        int tx = tid & 15, ty = tid >> 4;
        #pragma unroll
        for (int r = 0; r < 4; r++) {
            int kr = ty + r*16;
            size_t base = (size_t)(k0+kr)*N + n0 + tx*4;
            if (isbf) {
                ushort4 v = *(const ushort4*)((const u16*)src + base);
                tile[kr][tx*4+0] = v.x; tile[kr][tx*4+1] = v.y;
                tile[kr][tx*4+2] = v.z; tile[kr][tx*4+3] = v.w;
            } else {
                float4 f = *(const float4*)((const float*)src + base);
                tile[kr][tx*4+0] = f2bf(f.x); tile[kr][tx*4+1] = f2bf(f.y);
                tile[kr][tx*4+2] = f2bf(f.z); tile[kr][tx*4+3] = f2bf(f.w);
            }
        }
        __syncthreads();
        #pragma unroll
        for (int r = 0; r < 4; r++) {
            int nr = ty + r*16;
            ushort4 o;
            u16 v0 = tile[tx*4+0][nr], v1 = tile[tx*4+1][nr];
            u16 v2 = tile[tx*4+2][nr], v3 = tile[tx*4+3][nr];
            if (scale) {
                v0 = f2bf(bf2f(v0)*0.125f); v1 = f2bf(bf2f(v1)*0.125f);
                v2 = f2bf(bf2f(v2)*0.125f); v3 = f2bf(bf2f(v3)*0.125f);
            }
            o.x = v0; o.y = v1; o.z = v2; o.w = v3;
            *(ushort4*)&dst[(size_t)(n0+nr)*K + k0 + tx*4] = o;
        }
        return;
    }
    bid -= NB_TRANS;
    // layernorm row bid
    {
        int m = bid, t = tid;
        float v0, v1, v2, v3;
        if (isbf) {
            ushort4 xv = *(const ushort4*)((const u16*)xraw + (size_t)m*Dd + t*4);
            v0 = bf2f(xv.x); v1 = bf2f(xv.y); v2 = bf2f(xv.z); v3 = bf2f(xv.w);
        } else {
            float4 xf = *(const float4*)((const float*)xraw + (size_t)m*Dd + t*4);
            v0 = xf.x; v1 = xf.y; v2 = xf.z; v3 = xf.w;
        }
        float s  = v0+v1+v2+v3;
        float ss = v0*v0 + v1*v1 + v2*v2 + v3*v3;
        #pragma unroll
        for (int o = 32; o; o >>= 1){ s += __shfl_xor(s,o); ss += __shfl_xor(ss,o); }
        __shared__ float sb[8];
        int wid = t >> 6;
        if ((t & 63) == 0){ sb[wid] = s; sb[4+wid] = ss; }
        __syncthreads();
        s  = sb[0]+sb[1]+sb[2]+sb[3];
        ss = sb[4]+sb[5]+sb[6]+sb[7];
        float mu = s * (1.f/Dd);
        float var = fmaxf(ss * (1.f/Dd) - mu*mu, 0.f);
        float rs = rsqrtf(var + 1e-6f);
        float w0,w1,w2,w3,b0,b1,b2,b3;
        if (isbf) {
            ushort4 wv = *(const ushort4*)((const u16*)lnw_raw + t*4);
            ushort4 bv = *(const ushort4*)((const u16*)lnb_raw + t*4);
            w0=bf2f(wv.x); w1=bf2f(wv.y); w2=bf2f(wv.z); w3=bf2f(wv.w);
            b0=bf2f(bv.x); b1=bf2f(bv.y); b2=bf2f(bv.z); b3=bf2f(bv.w);
        } else {
            float4 wf = *(const float4*)((const float*)lnw_raw + t*4);
            float4 bfv = *(const float4*)((const float*)lnb_raw + t*4);
            w0=wf.x; w1=wf.y; w2=wf.z; w3=wf.w;
            b0=bfv.x; b1=bfv.y; b2=bfv.z; b3=bfv.w;
        }
        ushort4 o4;
        o4.x = f2bf((v0-mu)*rs*w0 + b0);
        o4.y = f2bf((v1-mu)*rs*w1 + b1);
        o4.z = f2bf((v2-mu)*rs*w2 + b2);
        o4.w = f2bf((v3-mu)*rs*w3 + b3);
        *(ushort4*)&xn[(size_t)m*Dd + t*4] = o4;
    }
}

// ---------------- bf16 MFMA GEMM core (r8 proven: dbuf + syncthreads) ----------------
// 128(M)x64(N) tile, 128 thr (2 waves). LDS dbuf 24 KB. global_load_lds width=16,
// scalar LDS base (wave-uniform + lane*16).
// epi: 0 bf16, bias split 2048; 1 bf16, split 512/1024 (+0.125*b2);
//      2 bf16, split 512; 3 +b0+xres, dtype probed from xres.
__device__ __forceinline__ void gemm_core(
    const u16* __restrict__ A, int lda,
    const u16* __restrict__ Bt, int ldb,
    void* __restrict__ Cout, int ldc, int K,
    const u16* __restrict__ b0, const u16* __restrict__ b1,
    const u16* __restrict__ b2,
    const void* __restrict__ xres,
    int epi, int m0, int n0, u16* As, u16* Bs)
{
    const int tid  = threadIdx.x;
    const int lane = tid & 63;
    const int ws   = __builtin_amdgcn_readfirstlane(tid >> 6);
    const int ln16 = lane & 15;
    const int quad = lane >> 4;

    f32x4 acc[4][4];
    #pragma unroll
    for (int i = 0; i < 4; i++)
        #pragma unroll
        for (int j = 0; j < 4; j++) acc[i][j] = (f32x4){0.f,0.f,0.f,0.f};

    auto stage = [&](int k0, u16* Ad, u16* Bd) {   // 6 DMA issues per wave
        #pragma unroll
        for (int p = 0; p < 4; p++) {
            int cb = p*128 + ws*64;
            int c  = cb + lane;
            int row = c >> 2, seg = (c & 3) << 3;
            __builtin_amdgcn_global_load_lds(
                (const __attribute__((address_space(1))) void*)(A + (size_t)(m0+row)*lda + k0 + seg),
                (__attribute__((address_space(3))) void*)(Ad + cb*8), 16, 0, 0);
        }
        #pragma unroll
        for (int p = 0; p < 2; p++) {
            int cb = p*128 + ws*64;
            int c  = cb + lane;
            int row = c >> 2, seg = (c & 3) << 3;
            __builtin_amdgcn_global_load_lds(
                (const __attribute__((address_space(1))) void*)(Bt + (size_t)(n0+row)*ldb + k0 + seg),
                (__attribute__((address_space(3))) void*)(Bd + cb*8), 16, 0, 0);
        }
    };

    const int nk = K >> 5;
    u16* A0 = As;           u16* A1 = As + 128*32;
    u16* B0 = Bs;           u16* B1 = Bs + 64*32;
    stage(0, A0, B0);
    __syncthreads();
    for (int kb = 0; kb < nk; kb++) {
        u16* Ac = (kb & 1) ? A1 : A0;
        u16* Bc = (kb & 1) ? B1 : B0;
        if (kb + 1 < nk) stage((kb+1) << 5, (kb & 1) ? A0 : A1, (kb & 1) ? B0 : B1);
        short8 af[4], bfr[4];
        #pragma unroll
        for (int mi = 0; mi < 4; mi++)
            af[mi] = *(const short8*)&Ac[(ws*64 + mi*16 + ln16)*32 + quad*8];
        #pragma unroll
        for (int ni = 0; ni < 4; ni++)
            bfr[ni] = *(const short8*)&Bc[(ni*16 + ln16)*32 + quad*8];
        #pragma unroll
        for (int mi = 0; mi < 4; mi++)
            #pragma unroll
            for (int ni = 0; ni < 4; ni++)
                acc[mi][ni] = __builtin_amdgcn_mfma_f32_16x16x32_bf16(
                    af[mi], bfr[ni], acc[mi][ni], 0, 0, 0);
        __syncthreads();
    }

    bool isbf = true;
    if (epi == 3) isbf = probe_bf16((const u16*)xres);
    #pragma unroll
    for (int mi = 0; mi < 4; mi++) {
        #pragma unroll
        for (int ni = 0; ni < 4; ni++) {
            int col = n0 + ni*16 + ln16;
            #pragma unroll
            for (int r = 0; r < 4; r++) {
                int row = m0 + ws*64 + mi*16 + quad*4 + r;
                float v = acc[mi][ni][r];
                if (epi == 0) {
                    v += (col < 2048) ? bf2f(b0[col]) : bf2f(b1[col-2048]);
                    ((u16*)Cout)[(size_t)row*ldc + col] = f2bf(v);
                } else if (epi == 1) {
                    v += (col < 512) ? bf2f(b0[col])
                       : (col < 1024 ? bf2f(b1[col-512]) : 0.125f*bf2f(b2[col-1024]));
                    ((u16*)Cout)[(size_t)row*ldc + col] = f2bf(v);
                } else if (epi == 2) {
                    v += (col < 512) ? bf2f(b0[col]) : bf2f(b1[col-512]);
                    ((u16*)Cout)[(size_t)row*ldc + col] = f2bf(v);
                } else {
                    size_t ridx = (size_t)row*Dd + col;
                    float res = isbf ? bf2f(((const u16*)xres)[ridx])
                                     : ((const float*)xres)[ridx];
                    v += bf2f(b0[col]) + res;
                    if (isbf) ((u16*)Cout)[(size_t)row*ldc + col] = f2bf(v);
                    else      ((float*)Cout)[(size_t)row*ldc + col] = v;
                }
            }
        }
    }
}

__global__ __launch_bounds__(128) void gemm_single_kernel(
    const u16* __restrict__ A, int lda,
    const u16* __restrict__ Bt, int ldb,
    void* __restrict__ Cout, int ldc, int K,
    const u16* __restrict__ b0, const u16* __restrict__ b1,
    const u16* __restrict__ b2,
    const void* __restrict__ xres, int epi)
{
    __shared__ u16 As[2*128*32];
    __shared__ u16 Bs[2*64*32];
    gemm_core(A, lda, Bt, ldb, Cout, ldc, K, b0, b1, b2, xres, epi,
              blockIdx.y*128, blockIdx.x*64, As, Bs);
}

// pair (sqk + vo GEMMs, 640 blocks) fused with gate GEMM (1024 blocks), 1D grid
__global__ __launch_bounds__(128) void pair_gate_kernel(
    const u16* __restrict__ A1, int lda1, const u16* __restrict__ Bt1,
    void* __restrict__ C1, int ldc1,
    const u16* __restrict__ b10, const u16* __restrict__ b11, const u16* __restrict__ b12,
    const u16* __restrict__ A2, int lda2, const u16* __restrict__ Bt2,
    void* __restrict__ C2, int ldc2,
    const u16* __restrict__ b20, const u16* __restrict__ b21,
    const u16* __restrict__ xc, const u16* __restrict__ small,
    float* __restrict__ ipre, float* __restrict__ fpre)
{
    __shared__ u16 As[2*128*32];
    __shared__ u16 Bs[2*64*32];
    int bid = blockIdx.x;
    if (bid < 640) {
        int bx = bid % 40, m0 = (bid / 40) * 128;
        if (bx < 24)
            gemm_core(A1, lda1, Bt1, 2048, C1, ldc1, 2048, b10, b11, b12,
                      nullptr, 1, m0, bx*64, As, Bs);
        else
            gemm_core(A2, lda2, Bt2, 2048, C2, ldc2, 2048, b20, b21, nullptr,
                      nullptr, 2, m0, (bx-24)*64, As, Bs);
        return;
    }
    // gate role: 2 waves, one m each
    int gb = bid - 640;
    int w = threadIdx.x >> 6, lane = threadIdx.x & 63;
    int m = gb*2 + w;
    const u16* Wi = small + SO_WI;
    const u16* Wf = small + SO_WF;
    float ai[8], af_[8];
    #pragma unroll
    for (int g = 0; g < 8; g++){ ai[g] = 0.f; af_[g] = 0.f; }
    for (int kb = 0; kb < 32; kb++) {
        int k = kb*64 + lane;
        float xv = bf2f(xc[(size_t)m*Pp + k]);
        uint4 wiu = *(const uint4*)&Wi[(size_t)k*8];
        uint4 wfu = *(const uint4*)&Wf[(size_t)k*8];
        const unsigned int* wi_ = (const unsigned int*)&wiu;
        const unsigned int* wf_ = (const unsigned int*)&wfu;
        #pragma unroll
        for (int i = 0; i < 4; i++) {
            ai[2*i]   += xv * bf2f((u16)(wi_[i] & 0xffff));
            ai[2*i+1] += xv * bf2f((u16)(wi_[i] >> 16));
            af_[2*i]  += xv * bf2f((u16)(wf_[i] & 0xffff));
            af_[2*i+1]+= xv * bf2f((u16)(wf_[i] >> 16));
        }
    }
    #pragma unroll
    for (int o = 32; o; o >>= 1) {
        #pragma unroll
        for (int g = 0; g < 8; g++) {
            ai[g]  += __shfl_xor(ai[g],  o);
            af_[g] += __shfl_xor(af_[g], o);
        }
    }
    if (lane == 0) {
        #pragma unroll
        for (int g = 0; g < 8; g++) {
            ipre[(size_t)m*8 + g] = 15.f * tanhf((ai[g]  + bf2f(small[SO_BI+g])) * (1.f/15.f));
            fpre[(size_t)m*8 + g] = 15.f * tanhf((af_[g] + bf2f(small[SO_BF+g])) * (1.f/15.f));
        }
    }
}

// ---------------- causal conv over feature axis + silu ----------------
__global__ __launch_bounds__(256) void conv_kernel(
    const u16* __restrict__ xtr, const u16* __restrict__ small,
    u16* __restrict__ xc)
{
    int m = blockIdx.x, t = threadIdx.x;
    int p0 = t * 8;
    const u16* rowp = xtr + (size_t)m * NAB;
    uint4 cur = *(const uint4*)&rowp[p0];
    uint4 prv;
    if (t > 0) prv = *(const uint4*)&rowp[p0-8];
    else { prv.x = prv.y = prv.z = prv.w = 0u; }
    float c16[16];
    const unsigned int* pu = (const unsigned int*)&prv;
    const unsigned int* cu = (const unsigned int*)&cur;
    #pragma unroll
    for (int i = 0; i < 4; i++) {
        c16[2*i]     = bf2f((u16)(pu[i] & 0xffff));
        c16[2*i+1]   = bf2f((u16)(pu[i] >> 16));
        c16[8+2*i]   = bf2f((u16)(cu[i] & 0xffff));
        c16[8+2*i+1] = bf2f((u16)(cu[i] >> 16));
    }
    float w0 = bf2f(small[SO_CW+0]), w1 = bf2f(small[SO_CW+1]);
    float w2 = bf2f(small[SO_CW+2]), w3 = bf2f(small[SO_CW+3]);
    float bb = bf2f(small[SO_CB]);
    unsigned int ou[4];
    #pragma unroll
    for (int jp = 0; jp < 4; jp++) {
        int j = 2*jp;
        float z0 = siluf_(bb + w0*c16[j+5] + w1*c16[j+6] + w2*c16[j+7] + w3*c16[j+8]);
        j++;
        float z1 = siluf_(bb + w0*c16[j+5] + w1*c16[j+6] + w2*c16[j+7] + w3*c16[j+8]);
        ou[jp] = (unsigned int)f2bf(z0) | ((unsigned int)f2bf(z1) << 16);
    }
    *(uint4*)&xc[(size_t)m*Pp + p0] = *(uint4*)ou;
}

// ---------------- parallel gate scan (max-plus) -> log-space chunk gates ----------------
__global__ __launch_bounds__(512) void gatescan_kernel(
    const float* __restrict__ ipre, const float* __restrict__ fpre,
    float* __restrict__ LPa, float* __restrict__ li, float* __restrict__ LPtot)
{
    int bh = blockIdx.x;
    int b = bh >> 3, h = bh & 7;
    int t = threadIdx.x;
    int lane = t & 63, w = t >> 6;
    size_t idx = ((size_t)(b*Tt + t))*8 + h;
    float iv = ipre[idx], fv = fpre[idx];
    float A = fv, Bv = iv;
    #pragma unroll
    for (int o = 1; o < 64; o <<= 1) {
        float pA = __shfl_up(A, o), pB = __shfl_up(Bv, o);
        if (lane >= o) {
            Bv = fmaxf(A + pB, Bv);
            A  = A + pA;
        }
    }
    __shared__ float aggA[8], aggB[8], mprev_s[8];
    if (lane == 63) { aggA[w] = A; aggB[w] = Bv; }
    __syncthreads();
    if (t == 0) {
        float m = 0.f;
        #pragma unroll
        for (int j = 0; j < 8; j++) {
            mprev_s[j] = m;
            m = fmaxf(aggA[j] + m, aggB[j]);
        }
    }
    __syncthreads();
    float mprev_w = mprev_s[w];
    float m_t = fmaxf(A + mprev_w, Bv);
    float m_tm1 = __shfl_up(m_t, 1);
    if (lane == 0) m_tm1 = mprev_w;
    float li_t = iv - m_t;
    float g = fv + m_tm1 - m_t;
    float lp = g;
    #pragma unroll
    for (int o = 1; o < 64; o <<= 1) {
        float p = __shfl_up(lp, o);
        if (lane >= o) lp += p;
    }
    LPa[(size_t)bh*Tt + t] = lp;
    li[(size_t)bh*Tt + t] = li_t;
    if (lane == 63) LPtot[bh*8 + w] = lp;
}

// ---------------- chunk outer products: B = sum_i w_i v_i k_i^T ----------------
__global__ __launch_bounds__(256) void chunk_outer_kernel(
    const u16* __restrict__ sqk, const u16* __restrict__ vo,
    const float* __restrict__ LPa, const float* __restrict__ li,
    const float* __restrict__ LPtot,
    float* __restrict__ B, float* __restrict__ bn)
{
    int blk = blockIdx.x;
    int bh = blk >> 3, c = blk & 7;
    int b = bh >> 3, h = bh & 7;
    __shared__ u16 kS[64*64], vS[64*64];
    __shared__ float wS[64];
    int tid = threadIdx.x;
    for (int r = tid; r < 512; r += 256) {
        int i = r >> 3, seg = (r & 7) * 8;
        size_t m = (size_t)b*Tt + c*64 + i;
        *(uint4*)&kS[i*64+seg] = *(const uint4*)&sqk[m*NC + 1024 + h*64 + seg];
        *(uint4*)&vS[i*64+seg] = *(const uint4*)&vo[m*NDm + h*64 + seg];
    }
    if (tid < 64) {
        float lpt = LPtot[bh*8 + c];
        int t = c*64 + tid;
        wS[tid] = __expf(lpt - LPa[(size_t)bh*Tt + t] + li[(size_t)bh*Tt + t]);
    }
    __syncthreads();
    int e = tid & 63, d0 = (tid >> 6) << 4;
    float acc[16];
    #pragma unroll
    for (int z = 0; z < 16; z++) acc[z] = 0.f;
    for (int i = 0; i < 64; i++) {
        float wk = wS[i] * bf2f(kS[i*64 + e]);
        float v16[16];
        unp8(&vS[i*64 + d0], v16);
        unp8(&vS[i*64 + d0 + 8], v16 + 8);
        #pragma unroll
        for (int z = 0; z < 16; z++) acc[z] += wk * v16[z];
    }
    float* Bp = B + (size_t)blk*4096;
    #pragma unroll
    for (int z = 0; z < 16; z++) Bp[(d0+z)*64 + e] = acc[z];
    if (tid < 64) {
        float a = 0.f;
        for (int i = 0; i < 64; i++) a += wS[i] * bf2f(kS[i*64 + tid]);
        bn[blk*64 + tid] = a;
    }
}

// ---------------- sequential chunk-state pass (8 steps) ----------------
__global__ __launch_bounds__(256) void state_pass_kernel(
    const float* __restrict__ B, const float* __restrict__ bn,
    const float* __restrict__ LPtot,
    float* __restrict__ Cinit, float* __restrict__ ninit)
{
    int bh = blockIdx.x, tid = threadIdx.x;
    float C[16];
    #pragma unroll
    for (int j = 0; j < 16; j++) C[j] = 0.f;
    float nv = 1.f;
    for (int c = 0; c < 8; c++) {
        float pc = __expf(LPtot[bh*8 + c]);
        const float* Bp = B + ((size_t)bh*8 + c)*4096;
        float* Cp = Cinit + ((size_t)bh*8 + c)*4096;
        #pragma unroll
        for (int j = 0; j < 16; j++) {
            Cp[tid*16 + j] = C[j];
            C[j] = pc*C[j] + Bp[tid*16 + j];
        }
        if (tid < 64) {
            ninit[(bh*8 + c)*64 + tid] = nv;
            nv = pc*nv + bn[(bh*8 + c)*64 + tid];
        }
    }
}

// ---------------- intra-chunk pass + fused o-gate/head-LN/skip/silu epilogue ----------------
__global__ __launch_bounds__(256) void intra_kernel(
    const u16* __restrict__ sqk, const u16* __restrict__ vo,
    const u16* __restrict__ xtr,
    const float* __restrict__ LPa, const float* __restrict__ li,
    const float* __restrict__ Cinit, const float* __restrict__ ninit,
    const u16* __restrict__ small, u16* __restrict__ y)
{
    int blk = blockIdx.x;
    int bh = blk >> 3, c = blk & 7;
    int b = bh >> 3, h = bh & 7;
    __shared__ u16 qS[64*64], kS[64*64], vS[64*64];
    __shared__ float GS[64*64];
    __shared__ float CS[64*64];
    __shared__ float lpS[64], liS[64], nS[64], denS[64];
    __shared__ float pS[4][64], pSS[4][64];
    int tid = threadIdx.x;
    for (int r = tid; r < 512; r += 256) {
        int i = r >> 3, seg = (r & 7) * 8;
        size_t m = (size_t)b*Tt + c*64 + i;
        *(uint4*)&qS[i*64+seg] = *(const uint4*)&sqk[m*NC + 512 + h*64 + seg];
        *(uint4*)&kS[i*64+seg] = *(const uint4*)&sqk[m*NC + 1024 + h*64 + seg];
        *(uint4*)&vS[i*64+seg] = *(const uint4*)&vo[m*NDm + h*64 + seg];
    }
    for (int r = tid; r < 4096; r += 256) CS[r] = Cinit[(size_t)blk*4096 + r];
    if (tid < 64) {
        lpS[tid] = LPa[(size_t)bh*Tt + c*64 + tid];
        liS[tid] = li[(size_t)bh*Tt + c*64 + tid];
        nS[tid]  = ninit[blk*64 + tid];
    }
    __syncthreads();

    // phase 1: masked scaled scores
    {
        int j = tid & 63, i0 = (tid >> 6) << 4;
        float acc[16];
        #pragma unroll
        for (int z = 0; z < 16; z++) acc[z] = 0.f;
        for (int seg = 0; seg < 64; seg += 8) {
            float q8[8];
            unp8(&qS[j*64 + seg], q8);
            #pragma unroll
            for (int z = 0; z < 16; z++) {
                float k8[8];
                unp8(&kS[(i0+z)*64 + seg], k8);
                float a = acc[z];
                #pragma unroll
                for (int e = 0; e < 8; e++) a += q8[e]*k8[e];
                acc[z] = a;
            }
        }
        float lpj = lpS[j];
        #pragma unroll
        for (int z = 0; z < 16; z++) {
            int i = i0 + z;
            GS[j*64 + i] = (i <= j) ? __expf(lpj - lpS[i] + liS[i]) * acc[z] : 0.f;
        }
    }
    __syncthreads();

    // phase 2: num = G'V + exp(lp_j)*Cinit q_j ; den
    int j = tid & 63, d0 = (tid >> 6) << 4;
    int seg4 = tid >> 6;
    float num[16];
    #pragma unroll
    for (int z = 0; z < 16; z++) num[z] = 0.f;
    for (int i = 0; i < 64; i++) {
        float g = GS[j*64 + i];
        float v16[16];
        unp8(&vS[i*64 + d0], v16);
        unp8(&vS[i*64 + d0 + 8], v16 + 8);
        #pragma unroll
        for (int z = 0; z < 16; z++) num[z] += g * v16[z];
    }
    float pj = __expf(lpS[j]);
    for (int es = 0; es < 16; es++) {
        uint2 uv = *(const uint2*)&qS[j*64 + es*4];
        float q0 = pj*bf2f((u16)(uv.x & 0xffff)), q1 = pj*bf2f((u16)(uv.x >> 16));
        float q2 = pj*bf2f((u16)(uv.y & 0xffff)), q3 = pj*bf2f((u16)(uv.y >> 16));
        #pragma unroll
        for (int z = 0; z < 16; z++) {
            float4 cv = *(const float4*)&CS[(d0+z)*64 + es*4];
            num[z] += q0*cv.x + q1*cv.y + q2*cv.z + q3*cv.w;
        }
    }
    if (tid < 64) {
        int jj = tid;
        float s = 0.f;
        for (int i = 0; i < 64; i++) s += GS[jj*64 + i];
        float dn = 0.f;
        for (int e = 0; e < 64; e++) dn += nS[e] * bf2f(qS[jj*64 + e]);
        denS[jj] = fmaxf(__expf(lpS[jj])*dn + s, 1.f);
    }
    __syncthreads();

    // fused epilogue: h = num/den; xv = sigmoid(o)*h; head-LN over 64 dims;
    // y = (hn + skip) * silu(r)
    size_t m = (size_t)b*Tt + c*64 + j;
    float rden = 1.f / denS[j];
    float o16[16];
    unp8(&vo[m*NDm + 512 + h*64 + d0], o16);
    unp8(&vo[m*NDm + 512 + h*64 + d0 + 8], o16 + 8);
    float xv[16];
    float s = 0.f, ss = 0.f;
    #pragma unroll
    for (int z = 0; z < 16; z++) {
        float hv = num[z] * rden;
        float t = sigmoidf_(o16[z]) * hv;
        xv[z] = t; s += t; ss += t*t;
    }
    pS[seg4][j] = s; pSS[seg4][j] = ss;
    __syncthreads();
    s  = pS[0][j] + pS[1][j] + pS[2][j] + pS[3][j];
    ss = pSS[0][j] + pSS[1][j] + pSS[2][j] + pSS[3][j];
    float mu = s * (1.f/64.f);
    float var = fmaxf(ss * (1.f/64.f) - mu*mu, 0.f);
    float rs = rsqrtf(var + 1e-6f);
    float hl[16], hb[16], sk[16], rr[16];
    unp8(&small[SO_HLNW + h*64 + d0], hl);  unp8(&small[SO_HLNW + h*64 + d0 + 8], hl + 8);
    unp8(&small[SO_HLNB + h*64 + d0], hb);  unp8(&small[SO_HLNB + h*64 + d0 + 8], hb + 8);
    unp8(&sqk[m*NC + h*64 + d0], sk);       unp8(&sqk[m*NC + h*64 + d0 + 8], sk + 8);
    unp8(&xtr[m*NAB + 2048 + h*64 + d0], rr); unp8(&xtr[m*NAB + 2048 + h*64 + d0 + 8], rr + 8);
    unsigned int w[8];
    #pragma unroll
    for (int z = 0; z < 8; z++) {
        float hn0 = (xv[2*z]   - mu)*rs*hl[2*z]   + hb[2*z];
        float hn1 = (xv[2*z+1] - mu)*rs*hl[2*z+1] + hb[2*z+1];
        float y0 = (hn0 + sk[2*z])   * siluf_(rr[2*z]);
        float y1 = (hn1 + sk[2*z+1]) * siluf_(rr[2*z+1]);
        w[z] = (unsigned int)f2bf(y0) | ((unsigned int)f2bf(y1) << 16);
    }
    u16* yp = &y[m*HD + h*64 + d0];
    *(uint4*)yp       = make_uint4(w[0], w[1], w[2], w[3]);
    *(uint4*)(yp + 8) = make_uint4(w[4], w[5], w[6], w[7]);
}

// ---------------- launch ----------------
extern "C" void kernel_launch(void* const* d_in, const int* in_sizes, int n_in,
                              void* d_out, int out_size, void* d_ws, size_t ws_size,
                              hipStream_t stream)
{
    (void)in_sizes; (void)n_in;
    const void* x      = d_in[0];
    const void* ln_w   = d_in[1];
    const void* ln_b   = d_in[2];
    const void* hln_w  = d_in[3];
    const void* hln_b  = d_in[4];
    const void* Wl     = d_in[5];
    const void* bl     = d_in[6];
    const void* Wr     = d_in[7];
    const void* br     = d_in[8];
    const void* conv_w = d_in[9];
    const void* conv_b = d_in[10];
    const void* Wskip  = d_in[11];
    const void* bskip  = d_in[12];
    const void* Wi     = d_in[13];
    const void* bi     = d_in[14];
    const void* Wf     = d_in[15];
    const void* bf     = d_in[16];
    const void* Wo     = d_in[17];
    const void* bo     = d_in[18];
    const void* Wq     = d_in[19];
    const void* bq     = d_in[20];
    const void* Wk     = d_in[21];
    const void* bk     = d_in[22];
    const void* Wv     = d_in[23];
    const void* bv     = d_in[24];
    const void* Wd     = d_in[25];
    const void* bd     = d_in[26];

    // ---- workspace layout ----
    const size_t SZ_flag  = 256;
    const size_t SZ_small = ((size_t)SO_END*2 + 255) & ~(size_t)255;
    const size_t SZ_WlrT  = (size_t)NAB*1024*2;
    const size_t SZ_WsqkT = (size_t)NC*2048*2;
    const size_t SZ_WvoT  = (size_t)NDm*2048*2;
    const size_t SZ_WdT   = (size_t)1024*512*2;
    const size_t SZ_xn    = (size_t)Mm*Dd*2;
    const size_t SZ_xtr   = (size_t)Mm*NAB*2;
    const size_t SZ_xc    = (size_t)Mm*Pp*2;
    const size_t SZ_sqk   = (size_t)Mm*NC*2;
    const size_t NEED = SZ_flag+SZ_small+SZ_WlrT+SZ_WsqkT+SZ_WvoT+SZ_WdT+SZ_xn+SZ_xtr+SZ_xc+SZ_sqk;

    if (ws_size < NEED) {
        int n4 = (out_size + 1) / 2;
        zero_out_kernel<<<(n4+255)/256, 256, 0, stream>>>((unsigned int*)d_out, n4);
        return;
    }

    char* wsp = (char*)d_ws;
    u16* small  = (u16*)(wsp + SZ_flag);
    u16* WlrT   = (u16*)(wsp + SZ_flag + SZ_small);
    u16* WsqkT  = (u16*)((char*)WlrT + SZ_WlrT);
    u16* WvoT   = (u16*)((char*)WsqkT + SZ_WsqkT);
    u16* WdT    = (u16*)((char*)WvoT + SZ_WvoT);
    char* regE  = (char*)WdT + SZ_WdT;
    u16* xn     = (u16*)regE;
    u16* xtr    = (u16*)(regE + SZ_xn);
    u16* xc     = (u16*)(regE + SZ_xn + SZ_xtr);
    u16* sqk    = (u16*)(regE + SZ_xn + SZ_xtr + SZ_xc);
    // aliases (lifetimes disjoint):
    u16* vo     = WlrT;                 // WlrT dead after gemm0
    u16* y      = xc;                   // xc dead after pair+gate launch
    float* ipre = (float*)regE;         // xn dead after gemm0
    float* fpre = (float*)(regE + 65536);
    float* LPa  = (float*)(regE + 2*65536);
    float* li   = (float*)(regE + 3*65536);
    float* LPtot= (float*)(regE + 4*65536);
    float* Bc   = (float*)WsqkT;                       // WsqkT dead after pair
    float* bn   = (float*)((char*)WsqkT + 4194304);
    float* ninit= (float*)((char*)WsqkT + 4259840);
    float* Cinit= (float*)WvoT;                        // WvoT dead after pair

    PtrsS SS;
    SS.p[0]=ln_w;  SS.p[1]=ln_b;   SS.p[2]=hln_w; SS.p[3]=hln_b; SS.p[4]=bl;
    SS.p[5]=br;    SS.p[6]=conv_w; SS.p[7]=conv_b;SS.p[8]=bskip; SS.p[9]=bi;
    SS.p[10]=bf;   SS.p[11]=bo;    SS.p[12]=bq;   SS.p[13]=bk;   SS.p[14]=bv;
    SS.p[15]=bd;   SS.p[16]=Wi;    SS.p[17]=Wf;
    Ptrs8 SW;
    SW.p[0]=Wl; SW.p[1]=Wr; SW.p[2]=Wskip; SW.p[3]=Wq;
    SW.p[4]=Wk; SW.p[5]=Wv; SW.p[6]=Wo;    SW.p[7]=Wd;

    // 1) fused canon + transpose + layernorm
    prep_kernel<<<NB_CANON + NB_TRANS + Mm, 256, 0, stream>>>(
        SS, SW, x, ln_w, ln_b, small, WlrT, WsqkT, WvoT, WdT, xn);
    // 2) xtr = xn @ [Wl|Wr] + [bl|br]
    gemm_single_kernel<<<dim3(NAB/64, Mm/128), 128, 0, stream>>>(
        xn, Dd, WlrT, 1024, xtr, NAB, 1024,
        small+SO_BL, small+SO_BR, nullptr, nullptr, 0);
    // 3) causal feature conv + silu
    conv_kernel<<<Mm, 256, 0, stream>>>(xtr, small, xc);
    // 4) pair GEMMs (sqk, vo) + gate GEMM fused
    pair_gate_kernel<<<640 + 1024, 128, 0, stream>>>(
        xc, Pp, WsqkT, sqk, NC, small+SO_BSKIP, small+SO_BQ, small+SO_BK,
        xtr, NAB, WvoT, vo, NDm, small+SO_BV, small+SO_BO,
        xc, small, ipre, fpre);
    // 5) log-space gate scan
    gatescan_kernel<<<32, 512, 0, stream>>>(ipre, fpre, LPa, li, LPtot);
    // 6) per-chunk outer products
    chunk_outer_kernel<<<256, 256, 0, stream>>>(sqk, vo, LPa, li, LPtot, Bc, bn);
    // 7) sequential chunk-state pass
    state_pass_kernel<<<32, 256, 0, stream>>>(Bc, bn, LPtot, Cinit, ninit);
    // 8) intra-chunk + fused epilogue -> y
    intra_kernel<<<256, 256, 0, stream>>>(sqk, vo, xtr, LPa, li, Cinit, ninit, small, y);
    // 9) out = (y @ Wd + bd + x), dtype probed
    gemm_single_kernel<<<dim3(Dd/64, Mm/128), 128, 0, stream>>>(
        y, HD, WdT, 512, d_out, Dd, 512,
        small+SO_BD, nullptr, nullptr, x, 3);
}